// Round 10
// baseline (577.421 us; speedup 1.0000x reference)
//
#include <hip/hip_runtime.h>
#include <cstdint>
#include <cstddef>

#define TSTEPS 60
#define NB 4096
#define HD 128

typedef __attribute__((ext_vector_type(8))) short short8;
typedef __attribute__((ext_vector_type(4))) float f32x4;

// ---------------- workspace layout (byte offsets) ----------------
#define WS_SJ    0
#define WS_SI    16384
#define WS_HID   32768                 // 4096*128 f32 = 2 MB
#define WS_HTH   2129920               // hid^T hi bf16, FRAGMENT-LINEAR, 1 MB
#define WS_HTL   3178496               // hid^T lo bf16, FRAGMENT-LINEAR, 1 MB
#define WS_F0H   4227072               // wih0 hi frags 49152 B
#define WS_F0L   (WS_F0H+49152)
#define WS_FR0H  (WS_F0L+49152)        // whh0 hi 98304 B
#define WS_FR0L  (WS_FR0H+98304)
#define WS_FR1H  (WS_FR0L+98304)
#define WS_FR1L  (WS_FR1H+98304)
#define WS_FR2H  (WS_FR1L+98304)
#define WS_FR2L  (WS_FR2H+98304)
#define WS_BASE  (WS_FR2L+98304)
#define WS_Y0P   WS_BASE               // packed y0 (hi|lo) uint: 256*60*2048*4
#define WS_FULL  (WS_Y0P + 125829120ULL)

// hT fragment-linear layout (R4): element (col c, batch n) lives at
//   (((c>>4)*8 + (n>>9))*16 + ((n>>5)&15))*512 + (((n>>3)&3)*16 + (c&15))*8 + (n&7)

__device__ __forceinline__ float b2f(unsigned short h){ return __uint_as_float(((unsigned)h)<<16); }
__device__ __forceinline__ unsigned short f2b(float f){
  unsigned u = __float_as_uint(f);
  u = (u + 0x7FFFu + ((u>>16)&1u)) >> 16;
  return (unsigned short)u;
}
__device__ __forceinline__ float sigm(float x){ return 1.0f/(1.0f + __expf(-x)); }
__device__ __forceinline__ float tanhfast(float x){
  float xc = fminf(fmaxf(x,-15.0f),15.0f);
  float e = __expf(2.0f*xc);
  return (e-1.0f)/(e+1.0f);
}
__device__ __forceinline__ float lrelu(float x){ return x > 0.0f ? x : 0.01f*x; }
__device__ __forceinline__ float ldr1(const void* p, size_t i, int f32){
  return f32 ? ((const float*)p)[i] : b2f(((const unsigned short*)p)[i]);
}
template<bool F32>
__device__ __forceinline__ float4 ldg4c(const void* p, size_t i){
  if (F32) return *(const float4*)((const float*)p + i);
  ushort4 u = *(const ushort4*)((const unsigned short*)p + i);
  float4 f; f.x=b2f(u.x); f.y=b2f(u.y); f.z=b2f(u.z); f.w=b2f(u.w); return f;
}
__device__ __forceinline__ f32x4 f4zero(){ f32x4 v = {0.f,0.f,0.f,0.f}; return v; }
__device__ __forceinline__ void pinv(short8& v){ asm volatile("" : "+v"(v)); }

// LDS-only barrier: drains LDS (lgkmcnt) but leaves global loads/stores in
// flight. Safe: in-flight global stores have no reader until next kernel;
// global-load consumers get compiler-inserted vmcnt waits.
__device__ __forceinline__ void ldsbar(){
  asm volatile("s_waitcnt lgkmcnt(0)\n\ts_barrier" ::: "memory");
}

// Block-uniform dtype probe (validated R7/R8): 1 = fp32, 0 = bf16.
__device__ int probe_f32(const void* p, int nprobe, volatile int* s){
  if (threadIdx.x == 0) *s = 0;
  __syncthreads();
  if ((int)threadIdx.x < nprobe) {
    float v = b2f(((const unsigned short*)p)[threadIdx.x]);
    if (!(v == v) || fabsf(v) > 1e4f) *s = 1;
  }
  __syncthreads();
  int r = *s;
  __syncthreads();
  return r;
}

__global__ void diag_kernel(float* out, float code){
  int i = blockIdx.x*256 + threadIdx.x;
  if (i < 4096) out[i] = code;
}

// ---------------- weight repack (validated R8) ----------------------------
__device__ void repack_mat(const void* src, int f32, int K, int nks,
                           unsigned short* hi, unsigned short* lo,
                           int tid, int nthr){
  int total = 384*K;
  for (int idx = tid; idx < total; idx += nthr) {
    int j = idx & 7, lane = (idx>>3)&63, t = idx>>9;
    int ks = t % nks, g = (t/nks)%3, w = t/(nks*3);
    int row = 16*(w + 8*g) + (lane & 15);
    int k   = ks*32 + ((lane>>4)<<3) + j;
    float v = f32 ? ((const float*)src)[(size_t)row*K + k]
                  : b2f(((const unsigned short*)src)[(size_t)row*K + k]);
    unsigned short h = f2b(v);
    hi[idx] = h;
    lo[idx] = f2b(v - b2f(h));
  }
}

__global__ __launch_bounds__(256) void repack_kernel(
    const void* wih0, const void* whh0, const void* wih1, const void* whh1,
    char* ws)
{
  __shared__ int sp;
  int f0 = probe_f32(wih0, 256, &sp);
  int f1 = probe_f32(whh0, 256, &sp);
  int f2 = probe_f32(wih1, 256, &sp);
  int f3 = probe_f32(whh1, 256, &sp);
  int tid  = blockIdx.x*256 + threadIdx.x;
  int nthr = gridDim.x*256;
  repack_mat(wih0, f0,  64, 2, (unsigned short*)(ws+WS_F0H),  (unsigned short*)(ws+WS_F0L),  tid, nthr);
  repack_mat(whh0, f1, 128, 4, (unsigned short*)(ws+WS_FR0H), (unsigned short*)(ws+WS_FR0L), tid, nthr);
  repack_mat(wih1, f2, 128, 4, (unsigned short*)(ws+WS_FR1H), (unsigned short*)(ws+WS_FR1L), tid, nthr);
  repack_mat(whh1, f3, 128, 4, (unsigned short*)(ws+WS_FR2H), (unsigned short*)(ws+WS_FR2L), tid, nthr);
}

#define MFMA __builtin_amdgcn_mfma_f32_16x16x32_bf16

// ---------------- PHASE 0: layer-0 GRU, K-SPLIT, 16 waves/block -----------
// (exact R7 form — the (1024,4) hint was a measured no-op and is dropped)
__global__ __launch_bounds__(1024)
void gru0_kernel(const void* __restrict__ xg,
                 const void* __restrict__ bih0, const void* __restrict__ bhh0,
                 const char* __restrict__ ws, unsigned* __restrict__ y0p)
{
  __shared__ __align__(16) unsigned short xbh[2][1152], xbl[2][1152];
  __shared__ __align__(16) unsigned short hbh[2][2176], hbl[2][2176];
  __shared__ __align__(16) float pex[8192];     // 16 slots * 4 g * 64 lanes * 2
  __shared__ int sp;
  const int tid  = threadIdx.x;
  const int W    = tid >> 6;        // 0..15
  const int cg   = W >> 1;          // channel group 0..7
  const int kh   = W & 1;           // K-half 0/1
  const int lane = tid & 63;
  const int ln   = lane & 15;
  const int kq   = lane >> 4;
  const int r0   = blockIdx.x * 16;

  int xf  = probe_f32(xg,   256, &sp);
  int fb0 = probe_f32(bih0, 256, &sp);
  int fh0 = probe_f32(bhh0, 256, &sp);

  const unsigned short* f0h  = (const unsigned short*)(ws+WS_F0H);
  const unsigned short* f0l  = (const unsigned short*)(ws+WS_F0L);
  const unsigned short* fr0h = (const unsigned short*)(ws+WS_FR0H);
  const unsigned short* fr0l = (const unsigned short*)(ws+WS_FR0L);

  // pinned x-part weights, my K-half only (6 frags = 24 VGPR)
  short8 X0h[3], X0l[3];
  #pragma unroll
  for (int g = 0; g < 3; ++g) {
    int fi = (cg*3+g)*2 + kh;
    X0h[g] = *(const short8*)&f0h[fi*512 + lane*8];
    X0l[g] = *(const short8*)&f0l[fi*512 + lane*8];
    pinv(X0h[g]); pinv(X0l[g]);
  }
  // pinned h-part weights, my K-half (12 frags = 48 VGPR)
  short8 R0h[3][2], R0l[3][2];
  #pragma unroll
  for (int g = 0; g < 3; ++g)
    #pragma unroll
    for (int jj = 0; jj < 2; ++jj) {
      int fi = (cg*3+g)*4 + kh*2 + jj;
      R0h[g][jj] = *(const short8*)&fr0h[fi*512 + lane*8];
      R0l[g][jj] = *(const short8*)&fr0l[fi*512 + lane*8];
      pinv(R0h[g][jj]); pinv(R0l[g][jj]);
    }

  const int nr = cg*16 + ln;
  float brc0 = ldr1(bih0,nr,fb0)     + ldr1(bhh0,nr,fh0);
  float bzc0 = ldr1(bih0,nr+128,fb0) + ldr1(bhh0,nr+128,fh0);
  float bin0 = ldr1(bih0,nr+256,fb0);
  float bhn0 = ldr1(bhh0,nr+256,fh0);

  for (int i = tid; i < 2176; i += 1024) { hbh[0][i] = 0; hbl[0][i] = 0; }
  const int xm = tid >> 5, xfc = (tid & 31)*2;    // staging role: tid < 512
  if (tid < 512) {
    size_t base = ((size_t)(r0+xm)*TSTEPS + 0)*64 + xfc;
    float v0, v1;
    if (xf) { float2 xv = *(const float2*)((const float*)xg + base); v0 = xv.x; v1 = xv.y; }
    else { ushort2 u = *(const ushort2*)((const unsigned short*)xg + base); v0 = b2f(u.x); v1 = b2f(u.y); }
    unsigned short a0 = f2b(v0), a1 = f2b(v1);
    unsigned short l0 = f2b(v0-b2f(a0)), l1 = f2b(v1-b2f(a1));
    *(unsigned*)&xbh[0][xm*72+xfc] = (unsigned)a0 | ((unsigned)a1<<16);
    *(unsigned*)&xbl[0][xm*72+xfc] = (unsigned)l0 | ((unsigned)l1<<16);
  }
  float h0o[2] = {0.f, 0.f};
  __syncthreads();

  #pragma unroll 1
  for (int t = 0; t < TSTEPS; ++t) {
    const int b0 = t & 1, b1 = b0 ^ 1;
    float v0 = 0.f, v1 = 0.f;
    const bool stg = (tid < 512) && (t+1 < TSTEPS);
    if (stg) {
      size_t base = ((size_t)(r0+xm)*TSTEPS + (t+1))*64 + xfc;
      if (xf) { float2 xv = *(const float2*)((const float*)xg + base); v0 = xv.x; v1 = xv.y; }
      else { ushort2 u = *(const ushort2*)((const unsigned short*)xg + base); v0 = b2f(u.x); v1 = b2f(u.y); }
    }

    // ---- partial MFMAs (my K-half) ----
    f32x4 acc[4];
    #pragma unroll
    for (int g = 0; g < 4; ++g) acc[g] = f4zero();
    {
      short8 axh = *(const short8*)&xbh[b0][ln*72 + kh*32 + kq*8];
      short8 axl = *(const short8*)&xbl[b0][ln*72 + kh*32 + kq*8];
      #pragma unroll
      for (int g = 0; g < 3; ++g) {
        acc[g] = MFMA(axh, X0h[g], acc[g], 0,0,0);
        acc[g] = MFMA(axh, X0l[g], acc[g], 0,0,0);
        acc[g] = MFMA(axl, X0h[g], acc[g], 0,0,0);
      }
    }
    #pragma unroll
    for (int jj = 0; jj < 2; ++jj) {
      short8 ahh = *(const short8*)&hbh[b0][ln*136 + (kh*2+jj)*32 + kq*8];
      short8 ahl = *(const short8*)&hbl[b0][ln*136 + (kh*2+jj)*32 + kq*8];
      #pragma unroll
      for (int g = 0; g < 3; ++g) {
        int tgt = (g==2) ? 3 : g;
        acc[tgt] = MFMA(ahh, R0h[g][jj], acc[tgt], 0,0,0);
        acc[tgt] = MFMA(ahh, R0l[g][jj], acc[tgt], 0,0,0);
        acc[tgt] = MFMA(ahl, R0h[g][jj], acc[tgt], 0,0,0);
      }
    }

    // ---- write partials for the rows my partner finalizes ----
    {
      int wbase = W*512 + lane*2;
      if (kh == 0) {
        #pragma unroll
        for (int g = 0; g < 4; ++g) {
          float2 wv; wv.x = acc[g][2]; wv.y = acc[g][3];
          *(float2*)&pex[wbase + g*128] = wv;
        }
      } else {
        #pragma unroll
        for (int g = 0; g < 4; ++g) {
          float2 wv; wv.x = acc[g][0]; wv.y = acc[g][1];
          *(float2*)&pex[wbase + g*128] = wv;
        }
      }
    }
    ldsbar();                 // barrier #1: partials visible

    // ---- combine with partner partials ----
    float c0[2], c1[2], c2[2], c3[2];
    {
      int pbase = (W^1)*512 + lane*2;
      float2 p0 = *(const float2*)&pex[pbase];
      float2 p1 = *(const float2*)&pex[pbase + 128];
      float2 p2 = *(const float2*)&pex[pbase + 256];
      float2 p3 = *(const float2*)&pex[pbase + 384];
      if (kh == 0) {
        c0[0]=acc[0][0]+p0.x; c0[1]=acc[0][1]+p0.y;
        c1[0]=acc[1][0]+p1.x; c1[1]=acc[1][1]+p1.y;
        c2[0]=acc[2][0]+p2.x; c2[1]=acc[2][1]+p2.y;
        c3[0]=acc[3][0]+p3.x; c3[1]=acc[3][1]+p3.y;
      } else {
        c0[0]=acc[0][2]+p0.x; c0[1]=acc[0][3]+p0.y;
        c1[0]=acc[1][2]+p1.x; c1[1]=acc[1][3]+p1.y;
        c2[0]=acc[2][2]+p2.x; c2[1]=acc[2][3]+p2.y;
        c3[0]=acc[3][2]+p3.x; c3[1]=acc[3][3]+p3.y;
      }
    }

    // ---- epilogue for my 2 rows ----
    unsigned short nh2[2], nl2[2];
    #pragma unroll
    for (int j = 0; j < 2; ++j) {
      float r  = sigm(c0[j] + brc0);
      float z  = sigm(c1[j] + bzc0);
      float nn = tanhfast(c2[j] + bin0 + r*(c3[j] + bhn0));
      float h  = nn + z*(h0o[j] - nn);
      h0o[j] = h;
      unsigned short hh = f2b(h);
      nh2[j] = hh; nl2[j] = f2b(h - b2f(hh));
    }
    const int rowb = kq*4 + kh*2;
    {
      size_t ybase = ((size_t)blockIdx.x*TSTEPS + t)*2048;
      #pragma unroll
      for (int j = 0; j < 2; ++j)
        y0p[ybase + (rowb+j)*128 + cg*16 + ln] =
            (unsigned)nh2[j] | ((unsigned)nl2[j] << 16);
    }
    #pragma unroll
    for (int j = 0; j < 2; ++j) {
      int off = (rowb+j)*136 + cg*16 + ln;
      hbh[b1][off] = nh2[j]; hbl[b1][off] = nl2[j];
    }
    if (stg) {
      unsigned short a0 = f2b(v0), a1 = f2b(v1);
      unsigned short l0 = f2b(v0-b2f(a0)), l1 = f2b(v1-b2f(a1));
      *(unsigned*)&xbh[b1][xm*72+xfc] = (unsigned)a0 | ((unsigned)a1<<16);
      *(unsigned*)&xbl[b1][xm*72+xfc] = (unsigned)l0 | ((unsigned)l1<<16);
    }
    ldsbar();                 // barrier #2
  }
}

// ---------------- PHASE 1: layer-1 GRU, 512 threads (R7-proven) -----------
__global__ __launch_bounds__(512) __attribute__((amdgpu_waves_per_eu(2,2)))
void gru1_kernel(const void* __restrict__ bih1, const void* __restrict__ bhh1,
                 const char* __restrict__ ws, const unsigned* __restrict__ y0p,
                 float* __restrict__ hidg,
                 unsigned short* __restrict__ hTh, unsigned short* __restrict__ hTl)
{
  __shared__ __align__(16) unsigned short wih1hL[49152];         // hi only
  __shared__ __align__(16) unsigned short ybh[2][2176], ybl[2][2176];
  __shared__ __align__(16) unsigned short h1bh[2][2176], h1bl[2][2176];
  __shared__ int sp;
  const int tid  = threadIdx.x;
  const int w    = tid >> 6;
  const int lane = tid & 63;
  const int ln   = lane & 15;
  const int kq   = lane >> 4;
  const int r0   = blockIdx.x * 16;

  int fb1 = probe_f32(bih1, 256, &sp);
  int fh1 = probe_f32(bhh1, 256, &sp);

  const unsigned short* fr1h = (const unsigned short*)(ws+WS_FR1H);
  const unsigned short* fr1l = (const unsigned short*)(ws+WS_FR1L);
  const unsigned short* fr2h = (const unsigned short*)(ws+WS_FR2H);
  const unsigned short* fr2l = (const unsigned short*)(ws+WS_FR2L);

  for (int i = tid*8; i < 49152; i += 4096) {
    *(ushort4*)&wih1hL[i]   = *(const ushort4*)&fr1h[i];
    *(ushort4*)&wih1hL[i+4] = *(const ushort4*)&fr1h[i+4];
  }

  // pinned wih1-hi for g=0,1 (8 frags = 32 VGPR)
  short8 W1hp[2][4];
  #pragma unroll
  for (int g = 0; g < 2; ++g)
    #pragma unroll
    for (int ks = 0; ks < 4; ++ks) {
      W1hp[g][ks] = *(const short8*)&fr1h[((w*3+g)*4+ks)*512 + lane*8];
      pinv(W1hp[g][ks]);
    }

  short8 W1l[3][4], R2h[3][4], R2l[3][4];
  #pragma unroll
  for (int g = 0; g < 3; ++g)
    #pragma unroll
    for (int ks = 0; ks < 4; ++ks) {
      int fi = (w*3+g)*4 + ks;
      W1l[g][ks] = *(const short8*)&fr1l[fi*512 + lane*8];
      R2h[g][ks] = *(const short8*)&fr2h[fi*512 + lane*8];
      R2l[g][ks] = *(const short8*)&fr2l[fi*512 + lane*8];
      pinv(W1l[g][ks]); pinv(R2h[g][ks]); pinv(R2l[g][ks]);
    }

  const int nr = 16*w + ln;
  float brc1 = ldr1(bih1,nr,fb1)     + ldr1(bhh1,nr,fh1);
  float bzc1 = ldr1(bih1,nr+128,fb1) + ldr1(bhh1,nr+128,fh1);
  float bin1 = ldr1(bih1,nr+256,fb1);
  float bhn1 = ldr1(bhh1,nr+256,fh1);

  for (int i = tid; i < 2176; i += 512) { h1bh[0][i] = 0; h1bl[0][i] = 0; }
  const int yi4 = tid*4, yrow = yi4 >> 7, ycol = yi4 & 127;
  // prologue: stage y(0) -> ybuf[0], y(1) -> ybuf[1]
  #pragma unroll
  for (int tt = 0; tt < 2; ++tt) {
    uint4 pv = *(const uint4*)&y0p[((size_t)blockIdx.x*TSTEPS + tt)*2048 + yi4];
    ushort4 vh, vl;
    vh.x=(unsigned short)(pv.x&0xffff); vl.x=(unsigned short)(pv.x>>16);
    vh.y=(unsigned short)(pv.y&0xffff); vl.y=(unsigned short)(pv.y>>16);
    vh.z=(unsigned short)(pv.z&0xffff); vl.z=(unsigned short)(pv.z>>16);
    vh.w=(unsigned short)(pv.w&0xffff); vl.w=(unsigned short)(pv.w>>16);
    *(ushort4*)&ybh[tt][yrow*136+ycol] = vh;
    *(ushort4*)&ybl[tt][yrow*136+ycol] = vl;
  }
  float h1o[4] = {0.f,0.f,0.f,0.f};
  __syncthreads();

  // accY = y-part of step 0 (reads ybuf[0])
  f32x4 accY[3];
  #pragma unroll
  for (int g = 0; g < 3; ++g) accY[g] = f4zero();
  #pragma unroll
  for (int ks = 0; ks < 4; ++ks) {
    short8 ayh = *(const short8*)&ybh[0][ln*136 + ks*32 + kq*8];
    short8 ayl = *(const short8*)&ybl[0][ln*136 + ks*32 + kq*8];
    #pragma unroll
    for (int g = 0; g < 3; ++g) {
      short8 bh;
      if (g < 2) bh = W1hp[g][ks];
      else       bh = *(const short8*)&wih1hL[((w*3+2)*4+ks)*512 + lane*8];
      accY[g] = MFMA(ayh, bh,         accY[g], 0,0,0);
      accY[g] = MFMA(ayh, W1l[g][ks], accY[g], 0,0,0);
      accY[g] = MFMA(ayl, bh,         accY[g], 0,0,0);
    }
  }

  #pragma unroll 1
  for (int t = 0; t < TSTEPS; ++t) {
    const int b0 = t & 1, b1 = b0 ^ 1;
    uint4 pv = {0,0,0,0};
    if (t+2 < TSTEPS)
      pv = *(const uint4*)&y0p[((size_t)blockIdx.x*TSTEPS + (t+2))*2048 + yi4];

    // seed with precomputed y-part; h-part accumulates on top
    f32x4 acc[4];
    acc[0] = accY[0]; acc[1] = accY[1]; acc[2] = accY[2]; acc[3] = f4zero();
    #pragma unroll
    for (int ks = 0; ks < 4; ++ks) {
      short8 a1h = *(const short8*)&h1bh[b0][ln*136 + ks*32 + kq*8];
      short8 a1l = *(const short8*)&h1bl[b0][ln*136 + ks*32 + kq*8];
      #pragma unroll
      for (int g = 0; g < 3; ++g) {
        int tgtH = (g==2) ? 3 : g;
        acc[tgtH] = MFMA(a1h, R2h[g][ks], acc[tgtH], 0,0,0);
        acc[tgtH] = MFMA(a1h, R2l[g][ks], acc[tgtH], 0,0,0);
        acc[tgtH] = MFMA(a1l, R2h[g][ks], acc[tgtH], 0,0,0);
      }
    }
    unsigned short nh[4], nl[4];
    #pragma unroll
    for (int rg = 0; rg < 4; ++rg) {
      float r  = sigm(acc[0][rg] + brc1);
      float z  = sigm(acc[1][rg] + bzc1);
      float nn = tanhfast(acc[2][rg] + bin1 + r*(acc[3][rg] + bhn1));
      float h  = nn + z*(h1o[rg] - nn);
      h1o[rg] = h;
      unsigned short hh = f2b(h);
      nh[rg] = hh; nl[rg] = f2b(h - b2f(hh));
    }
    #pragma unroll
    for (int rg = 0; rg < 4; ++rg) {
      int off = (kq*4+rg)*136 + w*16 + ln;
      h1bh[b1][off] = nh[rg]; h1bl[b1][off] = nl[rg];
    }
    // stage y(t+2) into ybuf[b0] (y(t) is dead — consumed by t-1's shadow)
    if (t+2 < TSTEPS) {
      ushort4 vh, vl;
      vh.x=(unsigned short)(pv.x&0xffff); vl.x=(unsigned short)(pv.x>>16);
      vh.y=(unsigned short)(pv.y&0xffff); vl.y=(unsigned short)(pv.y>>16);
      vh.z=(unsigned short)(pv.z&0xffff); vl.z=(unsigned short)(pv.z>>16);
      vh.w=(unsigned short)(pv.w&0xffff); vl.w=(unsigned short)(pv.w>>16);
      *(ushort4*)&ybh[b0][yrow*136+ycol] = vh;
      *(ushort4*)&ybl[b0][yrow*136+ycol] = vl;
    }
    // SHADOW: y-part MFMAs for step t+1 (h-independent)
    if (t+1 < TSTEPS) {
      #pragma unroll
      for (int g = 0; g < 3; ++g) accY[g] = f4zero();
      #pragma unroll
      for (int ks = 0; ks < 4; ++ks) {
        short8 ayh = *(const short8*)&ybh[b1][ln*136 + ks*32 + kq*8];
        short8 ayl = *(const short8*)&ybl[b1][ln*136 + ks*32 + kq*8];
        #pragma unroll
        for (int g = 0; g < 3; ++g) {
          short8 bh;
          if (g < 2) bh = W1hp[g][ks];
          else       bh = *(const short8*)&wih1hL[((w*3+2)*4+ks)*512 + lane*8];
          accY[g] = MFMA(ayh, bh,         accY[g], 0,0,0);
          accY[g] = MFMA(ayh, W1l[g][ks], accY[g], 0,0,0);
          accY[g] = MFMA(ayl, bh,         accY[g], 0,0,0);
        }
      }
    }
    ldsbar();          // single LDS-only barrier per step
  }

  // epilogue: hid (fp32) + hid^T hi/lo (bf16, FRAGMENT-LINEAR)
  {
    int c = w*16 + ln;
    #pragma unroll
    for (int rg = 0; rg < 4; ++rg)
      hidg[(size_t)(r0 + kq*4 + rg)*HD + c] = h1o[rg];
    #pragma unroll
    for (int rg = 0; rg < 4; ++rg) {
      unsigned short hh = f2b(h1o[rg]);
      unsigned short ll = f2b(h1o[rg] - b2f(hh));
      int n   = r0 + kq*4 + rg;
      int chn = n >> 9, ksn = (n >> 5) & 15, kqn = (n >> 3) & 3, jn = n & 7;
      size_t o = ((size_t)((w*8 + chn)*16 + ksn))*512
               + (size_t)(kqn*16 + ln)*8 + jn;
      hTh[o] = hh;
      hTl[o] = ll;
    }
  }
}

// ---------------- FALLBACK: R10 fused GRU (780 µs, proven) ----------------
__global__ __launch_bounds__(512, 1) void gru_fb_kernel(
    const void* __restrict__ xg,
    const void* __restrict__ bih0, const void* __restrict__ bhh0,
    const void* __restrict__ bih1, const void* __restrict__ bhh1,
    const char* __restrict__ ws, float* __restrict__ hidg,
    unsigned short* __restrict__ hTh, unsigned short* __restrict__ hTl)
{
  __shared__ __align__(16) unsigned short wih0L[49152];
  __shared__ __align__(16) unsigned short xhi[1152], xlo[1152];
  __shared__ __align__(16) unsigned short h0hi[2176], h0lo[2176];
  __shared__ __align__(16) unsigned short h1hi[2176], h1lo[2176];
  __shared__ int sp;
  const int tid  = threadIdx.x;
  const int w    = tid >> 6;
  const int lane = tid & 63;
  const int ln   = lane & 15;
  const int kq   = lane >> 4;
  const int r0   = blockIdx.x * 16;

  int xf  = probe_f32(xg,   256, &sp);
  int fb0 = probe_f32(bih0, 256, &sp);
  int fh0 = probe_f32(bhh0, 256, &sp);
  int fb1 = probe_f32(bih1, 256, &sp);
  int fh1 = probe_f32(bhh1, 256, &sp);

  const unsigned short* f0h  = (const unsigned short*)(ws+WS_F0H);
  const unsigned short* f0l  = (const unsigned short*)(ws+WS_F0L);
  const unsigned short* fr0h = (const unsigned short*)(ws+WS_FR0H);
  const unsigned short* fr0l = (const unsigned short*)(ws+WS_FR0L);
  const unsigned short* fr1h = (const unsigned short*)(ws+WS_FR1H);
  const unsigned short* fr1l = (const unsigned short*)(ws+WS_FR1L);
  const unsigned short* fr2h = (const unsigned short*)(ws+WS_FR2H);
  const unsigned short* fr2l = (const unsigned short*)(ws+WS_FR2L);

  for (int i = tid*8; i < 24576; i += 4096) {
    *(ushort4*)&wih0L[i]         = *(const ushort4*)&f0h[i];
    *(ushort4*)&wih0L[i+4]       = *(const ushort4*)&f0h[i+4];
    *(ushort4*)&wih0L[24576+i]   = *(const ushort4*)&f0l[i];
    *(ushort4*)&wih0L[24576+i+4] = *(const ushort4*)&f0l[i+4];
  }
  short8 R0h[3][4], R1h[3][4], R2h[3][4];
  #pragma unroll
  for (int g = 0; g < 3; ++g)
    #pragma unroll
    for (int ks = 0; ks < 4; ++ks) {
      int fi = (w*3+g)*4 + ks;
      R0h[g][ks] = *(const short8*)&fr0h[fi*512 + lane*8];
      R1h[g][ks] = *(const short8*)&fr1h[fi*512 + lane*8];
      R2h[g][ks] = *(const short8*)&fr2h[fi*512 + lane*8];
      pinv(R0h[g][ks]); pinv(R1h[g][ks]); pinv(R2h[g][ks]);
    }
  const int nr = 16*w + ln;
  float brc0 = ldr1(bih0,nr,fb0)     + ldr1(bhh0,nr,fh0);
  float bzc0 = ldr1(bih0,nr+128,fb0) + ldr1(bhh0,nr+128,fh0);
  float bin0 = ldr1(bih0,nr+256,fb0);
  float bhn0 = ldr1(bhh0,nr+256,fh0);
  float brc1 = ldr1(bih1,nr,fb1)     + ldr1(bhh1,nr,fh1);
  float bzc1 = ldr1(bih1,nr+128,fb1) + ldr1(bhh1,nr+128,fh1);
  float bin1 = ldr1(bih1,nr+256,fb1);
  float bhn1 = ldr1(bhh1,nr+256,fh1);

  for (int i = tid; i < 2176; i += 512) {
    h0hi[i] = 0; h0lo[i] = 0; h1hi[i] = 0; h1lo[i] = 0;
  }
  float h0o[4] = {0.f,0.f,0.f,0.f};
  float h1o[4] = {0.f,0.f,0.f,0.f};
  __syncthreads();

  #pragma unroll 1
  for (int t = 0; t < TSTEPS; ++t) {
    {
      int i0 = tid*2, m = i0 >> 6, f = i0 & 63;
      size_t base = ((size_t)(r0+m)*TSTEPS + t)*64 + f;
      float v0, v1;
      if (xf) { float2 xv = *(const float2*)((const float*)xg + base); v0 = xv.x; v1 = xv.y; }
      else { ushort2 u = *(const ushort2*)((const unsigned short*)xg + base); v0 = b2f(u.x); v1 = b2f(u.y); }
      unsigned short a0 = f2b(v0), a1 = f2b(v1);
      xhi[m*72+f] = a0;              xhi[m*72+f+1] = a1;
      xlo[m*72+f] = f2b(v0-b2f(a0)); xlo[m*72+f+1] = f2b(v1-b2f(a1));
    }
    __syncthreads();
    f32x4 acc[4];
    #pragma unroll
    for (int g = 0; g < 4; ++g) acc[g] = f4zero();
    #pragma unroll
    for (int ks = 0; ks < 2; ++ks) {
      short8 axh = *(const short8*)&xhi[ln*72 + ks*32 + kq*8];
      short8 axl = *(const short8*)&xlo[ln*72 + ks*32 + kq*8];
      #pragma unroll
      for (int g = 0; g < 3; ++g) {
        int fi = (w*3+g)*2 + ks;
        short8 bh = *(const short8*)&wih0L[fi*512 + lane*8];
        short8 bl = *(const short8*)&wih0L[24576 + fi*512 + lane*8];
        acc[g] = MFMA(axh, bh, acc[g], 0,0,0);
        acc[g] = MFMA(axh, bl, acc[g], 0,0,0);
        acc[g] = MFMA(axl, bh, acc[g], 0,0,0);
      }
    }
    #pragma unroll
    for (int ks = 0; ks < 4; ++ks) {
      short8 ahh = *(const short8*)&h0hi[ln*136 + ks*32 + kq*8];
      short8 ahl = *(const short8*)&h0lo[ln*136 + ks*32 + kq*8];
      #pragma unroll
      for (int g = 0; g < 3; ++g) {
        int tgt = (g==2) ? 3 : g;
        short8 bl = *(const short8*)&fr0l[((w*3+g)*4+ks)*512 + lane*8];
        acc[tgt] = MFMA(ahh, R0h[g][ks], acc[tgt], 0,0,0);
        acc[tgt] = MFMA(ahh, bl,         acc[tgt], 0,0,0);
        acc[tgt] = MFMA(ahl, R0h[g][ks], acc[tgt], 0,0,0);
      }
    }
    unsigned short nh[4], nl[4];
    #pragma unroll
    for (int rg = 0; rg < 4; ++rg) {
      float r  = sigm(acc[0][rg] + brc0);
      float z  = sigm(acc[1][rg] + bzc0);
      float nn = tanhfast(acc[2][rg] + bin0 + r*(acc[3][rg] + bhn0));
      float h  = nn + z*(h0o[rg] - nn);
      h0o[rg] = h;
      unsigned short hh = f2b(h);
      nh[rg] = hh; nl[rg] = f2b(h - b2f(hh));
    }
    __syncthreads();
    #pragma unroll
    for (int rg = 0; rg < 4; ++rg) {
      int off = (kq*4+rg)*136 + w*16 + ln;
      h0hi[off] = nh[rg]; h0lo[off] = nl[rg];
    }
    __syncthreads();
    #pragma unroll
    for (int g = 0; g < 4; ++g) acc[g] = f4zero();
    #pragma unroll
    for (int ks = 0; ks < 4; ++ks) {
      short8 ayh = *(const short8*)&h0hi[ln*136 + ks*32 + kq*8];
      short8 ayl = *(const short8*)&h0lo[ln*136 + ks*32 + kq*8];
      short8 a1h = *(const short8*)&h1hi[ln*136 + ks*32 + kq*8];
      short8 a1l = *(const short8*)&h1lo[ln*136 + ks*32 + kq*8];
      #pragma unroll
      for (int g = 0; g < 3; ++g) {
        int tgtI = (g==2) ? 2 : g;
        int tgtH = (g==2) ? 3 : g;
        short8 blI = *(const short8*)&fr1l[((w*3+g)*4+ks)*512 + lane*8];
        short8 blH = *(const short8*)&fr2l[((w*3+g)*4+ks)*512 + lane*8];
        acc[tgtI] = MFMA(ayh, R1h[g][ks], acc[tgtI], 0,0,0);
        acc[tgtI] = MFMA(ayh, blI,        acc[tgtI], 0,0,0);
        acc[tgtI] = MFMA(ayl, R1h[g][ks], acc[tgtI], 0,0,0);
        acc[tgtH] = MFMA(a1h, R2h[g][ks], acc[tgtH], 0,0,0);
        acc[tgtH] = MFMA(a1h, blH,        acc[tgtH], 0,0,0);
        acc[tgtH] = MFMA(a1l, R2h[g][ks], acc[tgtH], 0,0,0);
      }
    }
    #pragma unroll
    for (int rg = 0; rg < 4; ++rg) {
      float r  = sigm(acc[0][rg] + brc1);
      float z  = sigm(acc[1][rg] + bzc1);
      float nn = tanhfast(acc[2][rg] + bin1 + r*(acc[3][rg] + bhn1));
      float h  = nn + z*(h1o[rg] - nn);
      h1o[rg] = h;
      unsigned short hh = f2b(h);
      nh[rg] = hh; nl[rg] = f2b(h - b2f(hh));
    }
    __syncthreads();
    #pragma unroll
    for (int rg = 0; rg < 4; ++rg) {
      int off = (kq*4+rg)*136 + w*16 + ln;
      h1hi[off] = nh[rg]; h1lo[off] = nl[rg];
    }
  }
  {
    int c = w*16 + ln;
    #pragma unroll
    for (int rg = 0; rg < 4; ++rg)
      hidg[(size_t)(r0 + kq*4 + rg)*HD + c] = h1o[rg];
    #pragma unroll
    for (int rg = 0; rg < 4; ++rg) {
      unsigned short hh = f2b(h1o[rg]);
      unsigned short ll = f2b(h1o[rg] - b2f(hh));
      int n   = r0 + kq*4 + rg;
      int chn = n >> 9, ksn = (n >> 5) & 15, kqn = (n >> 3) & 3, jn = n & 7;
      size_t o = ((size_t)((w*8 + chn)*16 + ksn))*512
               + (size_t)(kqn*16 + ln)*8 + jn;
      hTh[o] = hh;
      hTl[o] = ll;
    }
  }
}

// ---------------- s_j / s_i prep (fp32), 256 threads (R7-proven) ----------
template<bool WT32>
__device__ void sprep_body(
    const float* hidg, const void* wt, const void* bt, const void* a,
    int f_bt, int f_a, float* sjg, float* sig, float* hL, float* redb)
{
  const int tid = threadIdx.x;
  const int r0  = blockIdx.x * 16;
  for (int i = tid; i < 2048; i += 256) hL[i] = hidg[(size_t)r0*128 + i];
  __syncthreads();
  const int r = tid >> 4, cg = tid & 15, c0 = cg*8;
  float sjp = 0.f, sip = 0.f;
  #pragma unroll 1
  for (int cc = 0; cc < 8; ++cc) {
    int cI = c0 + cc;
    float acc = ldr1(bt, cI, f_bt);
    #pragma unroll 4
    for (int kq = 0; kq < 32; ++kq) {
      int k = kq*4;
      float4 wv = ldg4c<WT32>(wt, (size_t)cI*128 + k);
      float4 h = *(const float4*)&hL[r*128 + k];
      acc += wv.x*h.x + wv.y*h.y + wv.z*h.z + wv.w*h.w;
    }
    sjp += acc * ldr1(a, cI, f_a);
    sip += acc * ldr1(a, cI + 128, f_a);
  }
  redb[(r*16+cg)*2]   = sjp;
  redb[(r*16+cg)*2+1] = sip;
  __syncthreads();
  if (tid < 32) {
    int r2 = tid >> 1, wh = tid & 1;
    float s = 0.f;
    for (int g = 0; g < 16; ++g) s += redb[(r2*16+g)*2 + wh];
    if (wh == 0) sjg[r0+r2] = s; else sig[r0+r2] = s;
  }
}

__global__ __launch_bounds__(256) void sprep_kernel(
    const float* hidg, const void* wt, const void* bt, const void* a,
    float* sjg, float* sig)
{
  __shared__ float hL[2048];
  __shared__ float redb[512];
  __shared__ int sp;
  int f_wt = probe_f32(wt, 256, &sp);
  int f_bt = probe_f32(bt, 128, &sp);
  int f_a  = probe_f32(a,  256, &sp);
  if (f_wt) sprep_body<true >(hidg, wt, bt, a, f_bt, f_a, sjg, sig, hL, redb);
  else      sprep_body<false>(hidg, wt, bt, a, f_bt, f_a, sjg, sig, hL, redb);
}

// ---------------- MFMA attention + residual + MLP tail --------------------
// R10: 8 query rows/block, 512 blocks -> ~56KB LDS -> 2 blocks/CU ->
// 4 waves/SIMD (2x latency hiding; attn was 90% stall at 2 waves/SIMD).
// Single-buffered P (R2 dbuf was ~null; dropping it is what fits 2 blocks).
// MFMA A-rows 8..15 read stale LDS -> garbage only in acc rows 8..15,
// which are never stored. accO's ch-accumulation order unchanged; Z/out
// reductions re-partitioned (fp32 reassoc, accepted).
template<bool PW32>
__device__ void attn_body(
    const float* sjg, const float* sig, const float* hidg,
    const unsigned short* hTh, const unsigned short* hTl,
    const void* wfc, const void* bfc, const void* wp1, const void* bp1,
    const void* wp2, const void* bp2,
    int f_bfc, int f_bp1, int f_wp2, float* outg,
    float* sjs, unsigned short* Pbuf, float* Obuf, float* redm,
    float* siL, float* miL, float* Zb)
{
  unsigned short* Phi = Pbuf;
  unsigned short* Plo = Pbuf + 8320;
  const int tid = threadIdx.x;
  const int w = tid >> 6, lane = tid & 63, ln = lane & 15, kq = lane >> 4;
  const int r0 = blockIdx.x * 8;

  for (int i = tid; i < 4096; i += 512) sjs[i] = sjg[i];
  __syncthreads();
  float mx = -1e30f;
  for (int i = tid; i < 4096; i += 512) mx = fmaxf(mx, sjs[i]);
  redm[tid] = mx;
  __syncthreads();
  for (int s = 256; s > 0; s >>= 1) {
    if (tid < s) redm[tid] = fmaxf(redm[tid], redm[tid+s]);
    __syncthreads();
  }
  if (tid < 8) {
    float si = sig[r0 + tid];
    siL[tid] = si;
    miL[tid] = lrelu(si + redm[0]);
  }
  __syncthreads();

  float zp[8];
  #pragma unroll
  for (int i = 0; i < 8; ++i) zp[i] = 0.f;
  f32x4 accO = f4zero();
  const int col = w*16 + ln;

  #pragma unroll 1
  for (int ch = 0; ch < 8; ++ch) {
    {
      float sjv = sjs[ch*512 + tid];
      #pragma unroll
      for (int i = 0; i < 8; ++i) {
        float v = lrelu(siL[i] + sjv);
        float p = __expf(v - miL[i]);
        zp[i] += p;
        unsigned short hh = f2b(p);
        Phi[i*520 + tid] = hh;
        Plo[i*520 + tid] = f2b(p - b2f(hh));
      }
    }
    __syncthreads();
    #pragma unroll
    for (int ks = 0; ks < 16; ++ks) {
      short8 Ah = *(const short8*)&Phi[ln*520 + ks*32 + kq*8];
      short8 Al = *(const short8*)&Plo[ln*520 + ks*32 + kq*8];
      size_t bo = ((size_t)((w*8 + ch)*16 + ks))*512 + (size_t)lane*8;
      short8 Bh = *(const short8*)&hTh[bo];
      short8 Bl = *(const short8*)&hTl[bo];
      accO = MFMA(Ah, Bh, accO, 0,0,0);
      accO = MFMA(Ah, Bl, accO, 0,0,0);
      accO = MFMA(Al, Bh, accO, 0,0,0);
    }
    __syncthreads();
  }

  // store only valid rows (kq*4+rg < 8)
  if (kq < 2) {
    #pragma unroll
    for (int rg = 0; rg < 4; ++rg)
      Obuf[(kq*4+rg)*128 + col] = accO[rg];
  }

  float* zarr = (float*)Pbuf;
  #pragma unroll
  for (int i = 0; i < 8; ++i) zarr[i*512 + tid] = zp[i];
  __syncthreads();
  {
    int row = tid >> 6, t0 = tid & 63;
    float s = 0.f;
    #pragma unroll
    for (int k = 0; k < 8; ++k) s += zarr[row*512 + t0 + 64*k];
    redm[row*64 + t0] = s;
  }
  __syncthreads();
  if (tid < 8) {
    float s = 0.f;
    for (int g = 0; g < 64; ++g) s += redm[tid*64 + g];
    Zb[tid] = s;
  }
  __syncthreads();

  {
    int e0 = tid*2, row = e0 >> 7, c = e0 & 127;
    float zi = Zb[row];
    #pragma unroll
    for (int e = 0; e < 2; ++e)
      Obuf[e0+e] = Obuf[e0+e]/zi + hidg[(size_t)(r0+row)*128 + c + e];
  }
  __syncthreads();

  float* h3f = sjs;
  {
    int o0 = tid*2, row = o0 >> 7, c = o0 & 127;
    #pragma unroll 1
    for (int e = 0; e < 2; ++e) {
      int cI = c + e;
      float acc = ldr1(bfc, cI, f_bfc);
      #pragma unroll 4
      for (int k4 = 0; k4 < 32; ++k4) {
        int k = k4*4;
        float4 wv = ldg4c<PW32>(wfc, (size_t)cI*128 + k);
        float4 h = *(const float4*)&Obuf[row*128 + k];
        acc += wv.x*h.x + wv.y*h.y + wv.z*h.z + wv.w*h.w;
      }
      h3f[row*128 + cI] = lrelu(acc);
    }
  }
  __syncthreads();

  float* h1f = (float*)Pbuf;
  {
    int o0 = tid*4, row = o0 >> 8, c = o0 & 255;
    #pragma unroll 1
    for (int e = 0; e < 4; ++e) {
      int cI = c + e;
      float acc = ldr1(bp1, cI, f_bp1);
      #pragma unroll 4
      for (int k4 = 0; k4 < 32; ++k4) {
        int k = k4*4;
        float4 wv = ldg4c<PW32>(wp1, (size_t)cI*128 + k);
        float4 h = *(const float4*)&h3f[row*128 + k];
        acc += wv.x*h.x + wv.y*h.y + wv.z*h.z + wv.w*h.w;
      }
      h1f[row*256 + cI] = 0.5f*acc*(1.0f + erff(acc*0.70710678118f));
    }
  }
  __syncthreads();

  {
    int row = tid >> 6, t0 = tid & 63;
    float s = 0.f;
    #pragma unroll
    for (int k = 0; k < 4; ++k) {
      int cI = t0 + 64*k;
      s += h1f[row*256 + cI] * ldr1(wp2, cI, f_wp2);
    }
    redm[row*64 + t0] = s;
  }
  __syncthreads();
  if (tid < 8) {
    float acc = ldr1(bp2, 0, f_bp1);
    for (int g = 0; g < 64; ++g) acc += redm[tid*64 + g];
    outg[r0 + tid] = acc;
  }
}

__global__ __launch_bounds__(512) void attn_kernel(
    const float* sjg, const float* sig, const float* hidg,
    const unsigned short* hTh, const unsigned short* hTl,
    const void* wfc, const void* bfc, const void* wp1, const void* bp1,
    const void* wp2, const void* bp2, float* outg)
{
  __shared__ float sjs[4096];
  __shared__ __align__(16) unsigned short Pbuf[16640];   // Phi|Plo (8 rows used)
  __shared__ float Obuf[1024];
  __shared__ float redm[512];
  __shared__ float siL[8], miL[8], Zb[8];
  __shared__ int sp;
  int f_wfc = probe_f32(wfc, 256, &sp);
  int f_bfc = probe_f32(bfc, 128, &sp);
  int f_bp1 = probe_f32(bp1, 256, &sp);
  int f_wp2 = probe_f32(wp2, 256, &sp);
  if (f_wfc) attn_body<true >(sjg, sig, hidg, hTh, hTl, wfc, bfc, wp1, bp1,
                              wp2, bp2, f_bfc, f_bp1, f_wp2, outg,
                              sjs, Pbuf, Obuf, redm, siL, miL, Zb);
  else       attn_body<false>(sjg, sig, hidg, hTh, hTl, wfc, bfc, wp1, bp1,
                              wp2, bp2, f_bfc, f_bp1, f_wp2, outg,
                              sjs, Pbuf, Obuf, redm, siL, miL, Zb);
}

extern "C" void kernel_launch(void* const* d_in, const int* in_sizes, int n_in,
                              void* d_out, int out_size, void* d_ws, size_t ws_size,
                              hipStream_t stream)
{
  float* out = (float*)d_out;
  const int expected[18] = {15728640,24576,49152,384,384,49152,49152,384,384,
                            16384,128,256,16384,128,32768,256,256,1};
  int bad = 0;
  if (n_in != 18 || out_size != 4096) bad = 1600;
  else for (int i = 0; i < 18; ++i) if (in_sizes[i] != expected[i]) { bad = 1600; break; }
  if (!bad && ws_size < (size_t)WS_BASE) bad = 1664;
  if (bad) { diag_kernel<<<16, 256, 0, stream>>>(out, (float)bad); return; }

  char* ws = (char*)d_ws;
  float*          sj  = (float*)(ws + WS_SJ);
  float*          si  = (float*)(ws + WS_SI);
  float*          hid = (float*)(ws + WS_HID);
  unsigned short* hTh = (unsigned short*)(ws + WS_HTH);
  unsigned short* hTl = (unsigned short*)(ws + WS_HTL);

  repack_kernel<<<256, 256, 0, stream>>>(d_in[1], d_in[2], d_in[5], d_in[6], ws);
  if (ws_size >= WS_FULL) {
    unsigned* y0p = (unsigned*)(ws + WS_Y0P);
    gru0_kernel<<<256, 1024, 0, stream>>>(d_in[0], d_in[3], d_in[4], ws, y0p);
    gru1_kernel<<<256, 512, 0, stream>>>(d_in[7], d_in[8], ws, y0p,
                                         hid, hTh, hTl);
  } else {
    gru_fb_kernel<<<256, 512, 0, stream>>>(d_in[0], d_in[3], d_in[4],
                                           d_in[7], d_in[8], ws, hid, hTh, hTl);
  }
  sprep_kernel<<<256, 256, 0, stream>>>(hid, d_in[9], d_in[10], d_in[11], sj, si);
  attn_kernel<<<512, 512, 0, stream>>>(sj, si, hid, hTh, hTl,
                                       d_in[12], d_in[13], d_in[14], d_in[15],
                                       d_in[16], d_in[17], out);
}

// Round 11
// 549.525 us; speedup vs baseline: 1.0508x; 1.0508x over previous
//
#include <hip/hip_runtime.h>
#include <cstdint>
#include <cstddef>

#define TSTEPS 60
#define NB 4096
#define HD 128

typedef __attribute__((ext_vector_type(8))) short short8;
typedef __attribute__((ext_vector_type(4))) float f32x4;

// ---------------- workspace layout (byte offsets) ----------------
#define WS_SJ    0
#define WS_SI    16384
#define WS_HID   32768                 // 4096*128 f32 = 2 MB
#define WS_HTH   2129920               // hid^T hi bf16, FRAGMENT-LINEAR, 1 MB
#define WS_HTL   3178496               // hid^T lo bf16, FRAGMENT-LINEAR, 1 MB
#define WS_F0H   4227072               // wih0 hi frags 49152 B
#define WS_F0L   (WS_F0H+49152)
#define WS_FR0H  (WS_F0L+49152)        // whh0 hi 98304 B
#define WS_FR0L  (WS_FR0H+98304)
#define WS_FR1H  (WS_FR0L+98304)
#define WS_FR1L  (WS_FR1H+98304)
#define WS_FR2H  (WS_FR1L+98304)
#define WS_FR2L  (WS_FR2H+98304)
#define WS_BASE  (WS_FR2L+98304)
#define WS_Y0P   WS_BASE               // packed y0 (hi|lo) uint: 256*60*2048*4
#define WS_FULL  (WS_Y0P + 125829120ULL)

// hT fragment-linear layout (R4): element (col c, batch n) lives at
//   (((c>>4)*8 + (n>>9))*16 + ((n>>5)&15))*512 + (((n>>3)&3)*16 + (c&15))*8 + (n&7)

__device__ __forceinline__ float b2f(unsigned short h){ return __uint_as_float(((unsigned)h)<<16); }
__device__ __forceinline__ unsigned short f2b(float f){
  unsigned u = __float_as_uint(f);
  u = (u + 0x7FFFu + ((u>>16)&1u)) >> 16;
  return (unsigned short)u;
}
__device__ __forceinline__ float sigm(float x){ return 1.0f/(1.0f + __expf(-x)); }
__device__ __forceinline__ float tanhfast(float x){
  float xc = fminf(fmaxf(x,-15.0f),15.0f);
  float e = __expf(2.0f*xc);
  return (e-1.0f)/(e+1.0f);
}
__device__ __forceinline__ float lrelu(float x){ return x > 0.0f ? x : 0.01f*x; }
__device__ __forceinline__ float ldr1(const void* p, size_t i, int f32){
  return f32 ? ((const float*)p)[i] : b2f(((const unsigned short*)p)[i]);
}
template<bool F32>
__device__ __forceinline__ float4 ldg4c(const void* p, size_t i){
  if (F32) return *(const float4*)((const float*)p + i);
  ushort4 u = *(const ushort4*)((const unsigned short*)p + i);
  float4 f; f.x=b2f(u.x); f.y=b2f(u.y); f.z=b2f(u.z); f.w=b2f(u.w); return f;
}
__device__ __forceinline__ f32x4 f4zero(){ f32x4 v = {0.f,0.f,0.f,0.f}; return v; }
__device__ __forceinline__ void pinv(short8& v){ asm volatile("" : "+v"(v)); }

// LDS-only barrier: drains LDS (lgkmcnt) but leaves global loads/stores in
// flight. Safe: in-flight global stores have no reader until next kernel;
// global-load consumers get compiler-inserted vmcnt waits.
__device__ __forceinline__ void ldsbar(){
  asm volatile("s_waitcnt lgkmcnt(0)\n\ts_barrier" ::: "memory");
}

// Block-uniform dtype probe (validated R7/R8): 1 = fp32, 0 = bf16.
__device__ int probe_f32(const void* p, int nprobe, volatile int* s){
  if (threadIdx.x == 0) *s = 0;
  __syncthreads();
  if ((int)threadIdx.x < nprobe) {
    float v = b2f(((const unsigned short*)p)[threadIdx.x]);
    if (!(v == v) || fabsf(v) > 1e4f) *s = 1;
  }
  __syncthreads();
  int r = *s;
  __syncthreads();
  return r;
}

__global__ void diag_kernel(float* out, float code){
  int i = blockIdx.x*256 + threadIdx.x;
  if (i < 4096) out[i] = code;
}

// ---------------- weight repack (validated R8) ----------------------------
__device__ void repack_mat(const void* src, int f32, int K, int nks,
                           unsigned short* hi, unsigned short* lo,
                           int tid, int nthr){
  int total = 384*K;
  for (int idx = tid; idx < total; idx += nthr) {
    int j = idx & 7, lane = (idx>>3)&63, t = idx>>9;
    int ks = t % nks, g = (t/nks)%3, w = t/(nks*3);
    int row = 16*(w + 8*g) + (lane & 15);
    int k   = ks*32 + ((lane>>4)<<3) + j;
    float v = f32 ? ((const float*)src)[(size_t)row*K + k]
                  : b2f(((const unsigned short*)src)[(size_t)row*K + k]);
    unsigned short h = f2b(v);
    hi[idx] = h;
    lo[idx] = f2b(v - b2f(h));
  }
}

__global__ __launch_bounds__(256) void repack_kernel(
    const void* wih0, const void* whh0, const void* wih1, const void* whh1,
    char* ws)
{
  __shared__ int sp;
  int f0 = probe_f32(wih0, 256, &sp);
  int f1 = probe_f32(whh0, 256, &sp);
  int f2 = probe_f32(wih1, 256, &sp);
  int f3 = probe_f32(whh1, 256, &sp);
  int tid  = blockIdx.x*256 + threadIdx.x;
  int nthr = gridDim.x*256;
  repack_mat(wih0, f0,  64, 2, (unsigned short*)(ws+WS_F0H),  (unsigned short*)(ws+WS_F0L),  tid, nthr);
  repack_mat(whh0, f1, 128, 4, (unsigned short*)(ws+WS_FR0H), (unsigned short*)(ws+WS_FR0L), tid, nthr);
  repack_mat(wih1, f2, 128, 4, (unsigned short*)(ws+WS_FR1H), (unsigned short*)(ws+WS_FR1L), tid, nthr);
  repack_mat(whh1, f3, 128, 4, (unsigned short*)(ws+WS_FR2H), (unsigned short*)(ws+WS_FR2L), tid, nthr);
}

#define MFMA __builtin_amdgcn_mfma_f32_16x16x32_bf16

// ---------------- PHASE 0: layer-0 GRU, K-SPLIT, 16 waves/block -----------
// (exact R7 form — proven ~155 µs)
__global__ __launch_bounds__(1024)
void gru0_kernel(const void* __restrict__ xg,
                 const void* __restrict__ bih0, const void* __restrict__ bhh0,
                 const char* __restrict__ ws, unsigned* __restrict__ y0p)
{
  __shared__ __align__(16) unsigned short xbh[2][1152], xbl[2][1152];
  __shared__ __align__(16) unsigned short hbh[2][2176], hbl[2][2176];
  __shared__ __align__(16) float pex[8192];     // 16 slots * 4 g * 64 lanes * 2
  __shared__ int sp;
  const int tid  = threadIdx.x;
  const int W    = tid >> 6;        // 0..15
  const int cg   = W >> 1;          // channel group 0..7
  const int kh   = W & 1;           // K-half 0/1
  const int lane = tid & 63;
  const int ln   = lane & 15;
  const int kq   = lane >> 4;
  const int r0   = blockIdx.x * 16;

  int xf  = probe_f32(xg,   256, &sp);
  int fb0 = probe_f32(bih0, 256, &sp);
  int fh0 = probe_f32(bhh0, 256, &sp);

  const unsigned short* f0h  = (const unsigned short*)(ws+WS_F0H);
  const unsigned short* f0l  = (const unsigned short*)(ws+WS_F0L);
  const unsigned short* fr0h = (const unsigned short*)(ws+WS_FR0H);
  const unsigned short* fr0l = (const unsigned short*)(ws+WS_FR0L);

  // pinned x-part weights, my K-half only (6 frags = 24 VGPR)
  short8 X0h[3], X0l[3];
  #pragma unroll
  for (int g = 0; g < 3; ++g) {
    int fi = (cg*3+g)*2 + kh;
    X0h[g] = *(const short8*)&f0h[fi*512 + lane*8];
    X0l[g] = *(const short8*)&f0l[fi*512 + lane*8];
    pinv(X0h[g]); pinv(X0l[g]);
  }
  // pinned h-part weights, my K-half (12 frags = 48 VGPR)
  short8 R0h[3][2], R0l[3][2];
  #pragma unroll
  for (int g = 0; g < 3; ++g)
    #pragma unroll
    for (int jj = 0; jj < 2; ++jj) {
      int fi = (cg*3+g)*4 + kh*2 + jj;
      R0h[g][jj] = *(const short8*)&fr0h[fi*512 + lane*8];
      R0l[g][jj] = *(const short8*)&fr0l[fi*512 + lane*8];
      pinv(R0h[g][jj]); pinv(R0l[g][jj]);
    }

  const int nr = cg*16 + ln;
  float brc0 = ldr1(bih0,nr,fb0)     + ldr1(bhh0,nr,fh0);
  float bzc0 = ldr1(bih0,nr+128,fb0) + ldr1(bhh0,nr+128,fh0);
  float bin0 = ldr1(bih0,nr+256,fb0);
  float bhn0 = ldr1(bhh0,nr+256,fh0);

  for (int i = tid; i < 2176; i += 1024) { hbh[0][i] = 0; hbl[0][i] = 0; }
  const int xm = tid >> 5, xfc = (tid & 31)*2;    // staging role: tid < 512
  if (tid < 512) {
    size_t base = ((size_t)(r0+xm)*TSTEPS + 0)*64 + xfc;
    float v0, v1;
    if (xf) { float2 xv = *(const float2*)((const float*)xg + base); v0 = xv.x; v1 = xv.y; }
    else { ushort2 u = *(const ushort2*)((const unsigned short*)xg + base); v0 = b2f(u.x); v1 = b2f(u.y); }
    unsigned short a0 = f2b(v0), a1 = f2b(v1);
    unsigned short l0 = f2b(v0-b2f(a0)), l1 = f2b(v1-b2f(a1));
    *(unsigned*)&xbh[0][xm*72+xfc] = (unsigned)a0 | ((unsigned)a1<<16);
    *(unsigned*)&xbl[0][xm*72+xfc] = (unsigned)l0 | ((unsigned)l1<<16);
  }
  float h0o[2] = {0.f, 0.f};
  __syncthreads();

  #pragma unroll 1
  for (int t = 0; t < TSTEPS; ++t) {
    const int b0 = t & 1, b1 = b0 ^ 1;
    float v0 = 0.f, v1 = 0.f;
    const bool stg = (tid < 512) && (t+1 < TSTEPS);
    if (stg) {
      size_t base = ((size_t)(r0+xm)*TSTEPS + (t+1))*64 + xfc;
      if (xf) { float2 xv = *(const float2*)((const float*)xg + base); v0 = xv.x; v1 = xv.y; }
      else { ushort2 u = *(const ushort2*)((const unsigned short*)xg + base); v0 = b2f(u.x); v1 = b2f(u.y); }
    }

    // ---- partial MFMAs (my K-half) ----
    f32x4 acc[4];
    #pragma unroll
    for (int g = 0; g < 4; ++g) acc[g] = f4zero();
    {
      short8 axh = *(const short8*)&xbh[b0][ln*72 + kh*32 + kq*8];
      short8 axl = *(const short8*)&xbl[b0][ln*72 + kh*32 + kq*8];
      #pragma unroll
      for (int g = 0; g < 3; ++g) {
        acc[g] = MFMA(axh, X0h[g], acc[g], 0,0,0);
        acc[g] = MFMA(axh, X0l[g], acc[g], 0,0,0);
        acc[g] = MFMA(axl, X0h[g], acc[g], 0,0,0);
      }
    }
    #pragma unroll
    for (int jj = 0; jj < 2; ++jj) {
      short8 ahh = *(const short8*)&hbh[b0][ln*136 + (kh*2+jj)*32 + kq*8];
      short8 ahl = *(const short8*)&hbl[b0][ln*136 + (kh*2+jj)*32 + kq*8];
      #pragma unroll
      for (int g = 0; g < 3; ++g) {
        int tgt = (g==2) ? 3 : g;
        acc[tgt] = MFMA(ahh, R0h[g][jj], acc[tgt], 0,0,0);
        acc[tgt] = MFMA(ahh, R0l[g][jj], acc[tgt], 0,0,0);
        acc[tgt] = MFMA(ahl, R0h[g][jj], acc[tgt], 0,0,0);
      }
    }

    // ---- write partials for the rows my partner finalizes ----
    {
      int wbase = W*512 + lane*2;
      if (kh == 0) {
        #pragma unroll
        for (int g = 0; g < 4; ++g) {
          float2 wv; wv.x = acc[g][2]; wv.y = acc[g][3];
          *(float2*)&pex[wbase + g*128] = wv;
        }
      } else {
        #pragma unroll
        for (int g = 0; g < 4; ++g) {
          float2 wv; wv.x = acc[g][0]; wv.y = acc[g][1];
          *(float2*)&pex[wbase + g*128] = wv;
        }
      }
    }
    ldsbar();                 // barrier #1: partials visible

    // ---- combine with partner partials ----
    float c0[2], c1[2], c2[2], c3[2];
    {
      int pbase = (W^1)*512 + lane*2;
      float2 p0 = *(const float2*)&pex[pbase];
      float2 p1 = *(const float2*)&pex[pbase + 128];
      float2 p2 = *(const float2*)&pex[pbase + 256];
      float2 p3 = *(const float2*)&pex[pbase + 384];
      if (kh == 0) {
        c0[0]=acc[0][0]+p0.x; c0[1]=acc[0][1]+p0.y;
        c1[0]=acc[1][0]+p1.x; c1[1]=acc[1][1]+p1.y;
        c2[0]=acc[2][0]+p2.x; c2[1]=acc[2][1]+p2.y;
        c3[0]=acc[3][0]+p3.x; c3[1]=acc[3][1]+p3.y;
      } else {
        c0[0]=acc[0][2]+p0.x; c0[1]=acc[0][3]+p0.y;
        c1[0]=acc[1][2]+p1.x; c1[1]=acc[1][3]+p1.y;
        c2[0]=acc[2][2]+p2.x; c2[1]=acc[2][3]+p2.y;
        c3[0]=acc[3][2]+p3.x; c3[1]=acc[3][3]+p3.y;
      }
    }

    // ---- epilogue for my 2 rows ----
    unsigned short nh2[2], nl2[2];
    #pragma unroll
    for (int j = 0; j < 2; ++j) {
      float r  = sigm(c0[j] + brc0);
      float z  = sigm(c1[j] + bzc0);
      float nn = tanhfast(c2[j] + bin0 + r*(c3[j] + bhn0));
      float h  = nn + z*(h0o[j] - nn);
      h0o[j] = h;
      unsigned short hh = f2b(h);
      nh2[j] = hh; nl2[j] = f2b(h - b2f(hh));
    }
    const int rowb = kq*4 + kh*2;
    {
      size_t ybase = ((size_t)blockIdx.x*TSTEPS + t)*2048;
      #pragma unroll
      for (int j = 0; j < 2; ++j)
        y0p[ybase + (rowb+j)*128 + cg*16 + ln] =
            (unsigned)nh2[j] | ((unsigned)nl2[j] << 16);
    }
    #pragma unroll
    for (int j = 0; j < 2; ++j) {
      int off = (rowb+j)*136 + cg*16 + ln;
      hbh[b1][off] = nh2[j]; hbl[b1][off] = nl2[j];
    }
    if (stg) {
      unsigned short a0 = f2b(v0), a1 = f2b(v1);
      unsigned short l0 = f2b(v0-b2f(a0)), l1 = f2b(v1-b2f(a1));
      *(unsigned*)&xbh[b1][xm*72+xfc] = (unsigned)a0 | ((unsigned)a1<<16);
      *(unsigned*)&xbl[b1][xm*72+xfc] = (unsigned)l0 | ((unsigned)l1<<16);
    }
    ldsbar();                 // barrier #2
  }
}

// ---------------- PHASE 1: layer-1 GRU, 512 threads (R7-proven) -----------
__global__ __launch_bounds__(512) __attribute__((amdgpu_waves_per_eu(2,2)))
void gru1_kernel(const void* __restrict__ bih1, const void* __restrict__ bhh1,
                 const char* __restrict__ ws, const unsigned* __restrict__ y0p,
                 float* __restrict__ hidg,
                 unsigned short* __restrict__ hTh, unsigned short* __restrict__ hTl)
{
  __shared__ __align__(16) unsigned short wih1hL[49152];         // hi only
  __shared__ __align__(16) unsigned short ybh[2][2176], ybl[2][2176];
  __shared__ __align__(16) unsigned short h1bh[2][2176], h1bl[2][2176];
  __shared__ int sp;
  const int tid  = threadIdx.x;
  const int w    = tid >> 6;
  const int lane = tid & 63;
  const int ln   = lane & 15;
  const int kq   = lane >> 4;
  const int r0   = blockIdx.x * 16;

  int fb1 = probe_f32(bih1, 256, &sp);
  int fh1 = probe_f32(bhh1, 256, &sp);

  const unsigned short* fr1h = (const unsigned short*)(ws+WS_FR1H);
  const unsigned short* fr1l = (const unsigned short*)(ws+WS_FR1L);
  const unsigned short* fr2h = (const unsigned short*)(ws+WS_FR2H);
  const unsigned short* fr2l = (const unsigned short*)(ws+WS_FR2L);

  for (int i = tid*8; i < 49152; i += 4096) {
    *(ushort4*)&wih1hL[i]   = *(const ushort4*)&fr1h[i];
    *(ushort4*)&wih1hL[i+4] = *(const ushort4*)&fr1h[i+4];
  }

  // pinned wih1-hi for g=0,1 (8 frags = 32 VGPR)
  short8 W1hp[2][4];
  #pragma unroll
  for (int g = 0; g < 2; ++g)
    #pragma unroll
    for (int ks = 0; ks < 4; ++ks) {
      W1hp[g][ks] = *(const short8*)&fr1h[((w*3+g)*4+ks)*512 + lane*8];
      pinv(W1hp[g][ks]);
    }

  short8 W1l[3][4], R2h[3][4], R2l[3][4];
  #pragma unroll
  for (int g = 0; g < 3; ++g)
    #pragma unroll
    for (int ks = 0; ks < 4; ++ks) {
      int fi = (w*3+g)*4 + ks;
      W1l[g][ks] = *(const short8*)&fr1l[fi*512 + lane*8];
      R2h[g][ks] = *(const short8*)&fr2h[fi*512 + lane*8];
      R2l[g][ks] = *(const short8*)&fr2l[fi*512 + lane*8];
      pinv(W1l[g][ks]); pinv(R2h[g][ks]); pinv(R2l[g][ks]);
    }

  const int nr = 16*w + ln;
  float brc1 = ldr1(bih1,nr,fb1)     + ldr1(bhh1,nr,fh1);
  float bzc1 = ldr1(bih1,nr+128,fb1) + ldr1(bhh1,nr+128,fh1);
  float bin1 = ldr1(bih1,nr+256,fb1);
  float bhn1 = ldr1(bhh1,nr+256,fh1);

  for (int i = tid; i < 2176; i += 512) { h1bh[0][i] = 0; h1bl[0][i] = 0; }
  const int yi4 = tid*4, yrow = yi4 >> 7, ycol = yi4 & 127;
  // prologue: stage y(0) -> ybuf[0], y(1) -> ybuf[1]
  #pragma unroll
  for (int tt = 0; tt < 2; ++tt) {
    uint4 pv = *(const uint4*)&y0p[((size_t)blockIdx.x*TSTEPS + tt)*2048 + yi4];
    ushort4 vh, vl;
    vh.x=(unsigned short)(pv.x&0xffff); vl.x=(unsigned short)(pv.x>>16);
    vh.y=(unsigned short)(pv.y&0xffff); vl.y=(unsigned short)(pv.y>>16);
    vh.z=(unsigned short)(pv.z&0xffff); vl.z=(unsigned short)(pv.z>>16);
    vh.w=(unsigned short)(pv.w&0xffff); vl.w=(unsigned short)(pv.w>>16);
    *(ushort4*)&ybh[tt][yrow*136+ycol] = vh;
    *(ushort4*)&ybl[tt][yrow*136+ycol] = vl;
  }
  float h1o[4] = {0.f,0.f,0.f,0.f};
  __syncthreads();

  // accY = y-part of step 0 (reads ybuf[0])
  f32x4 accY[3];
  #pragma unroll
  for (int g = 0; g < 3; ++g) accY[g] = f4zero();
  #pragma unroll
  for (int ks = 0; ks < 4; ++ks) {
    short8 ayh = *(const short8*)&ybh[0][ln*136 + ks*32 + kq*8];
    short8 ayl = *(const short8*)&ybl[0][ln*136 + ks*32 + kq*8];
    #pragma unroll
    for (int g = 0; g < 3; ++g) {
      short8 bh;
      if (g < 2) bh = W1hp[g][ks];
      else       bh = *(const short8*)&wih1hL[((w*3+2)*4+ks)*512 + lane*8];
      accY[g] = MFMA(ayh, bh,         accY[g], 0,0,0);
      accY[g] = MFMA(ayh, W1l[g][ks], accY[g], 0,0,0);
      accY[g] = MFMA(ayl, bh,         accY[g], 0,0,0);
    }
  }

  #pragma unroll 1
  for (int t = 0; t < TSTEPS; ++t) {
    const int b0 = t & 1, b1 = b0 ^ 1;
    uint4 pv = {0,0,0,0};
    if (t+2 < TSTEPS)
      pv = *(const uint4*)&y0p[((size_t)blockIdx.x*TSTEPS + (t+2))*2048 + yi4];

    // seed with precomputed y-part; h-part accumulates on top
    f32x4 acc[4];
    acc[0] = accY[0]; acc[1] = accY[1]; acc[2] = accY[2]; acc[3] = f4zero();
    #pragma unroll
    for (int ks = 0; ks < 4; ++ks) {
      short8 a1h = *(const short8*)&h1bh[b0][ln*136 + ks*32 + kq*8];
      short8 a1l = *(const short8*)&h1bl[b0][ln*136 + ks*32 + kq*8];
      #pragma unroll
      for (int g = 0; g < 3; ++g) {
        int tgtH = (g==2) ? 3 : g;
        acc[tgtH] = MFMA(a1h, R2h[g][ks], acc[tgtH], 0,0,0);
        acc[tgtH] = MFMA(a1h, R2l[g][ks], acc[tgtH], 0,0,0);
        acc[tgtH] = MFMA(a1l, R2h[g][ks], acc[tgtH], 0,0,0);
      }
    }
    unsigned short nh[4], nl[4];
    #pragma unroll
    for (int rg = 0; rg < 4; ++rg) {
      float r  = sigm(acc[0][rg] + brc1);
      float z  = sigm(acc[1][rg] + bzc1);
      float nn = tanhfast(acc[2][rg] + bin1 + r*(acc[3][rg] + bhn1));
      float h  = nn + z*(h1o[rg] - nn);
      h1o[rg] = h;
      unsigned short hh = f2b(h);
      nh[rg] = hh; nl[rg] = f2b(h - b2f(hh));
    }
    #pragma unroll
    for (int rg = 0; rg < 4; ++rg) {
      int off = (kq*4+rg)*136 + w*16 + ln;
      h1bh[b1][off] = nh[rg]; h1bl[b1][off] = nl[rg];
    }
    // stage y(t+2) into ybuf[b0] (y(t) is dead — consumed by t-1's shadow)
    if (t+2 < TSTEPS) {
      ushort4 vh, vl;
      vh.x=(unsigned short)(pv.x&0xffff); vl.x=(unsigned short)(pv.x>>16);
      vh.y=(unsigned short)(pv.y&0xffff); vl.y=(unsigned short)(pv.y>>16);
      vh.z=(unsigned short)(pv.z&0xffff); vl.z=(unsigned short)(pv.z>>16);
      vh.w=(unsigned short)(pv.w&0xffff); vl.w=(unsigned short)(pv.w>>16);
      *(ushort4*)&ybh[b0][yrow*136+ycol] = vh;
      *(ushort4*)&ybl[b0][yrow*136+ycol] = vl;
    }
    // SHADOW: y-part MFMAs for step t+1 (h-independent)
    if (t+1 < TSTEPS) {
      #pragma unroll
      for (int g = 0; g < 3; ++g) accY[g] = f4zero();
      #pragma unroll
      for (int ks = 0; ks < 4; ++ks) {
        short8 ayh = *(const short8*)&ybh[b1][ln*136 + ks*32 + kq*8];
        short8 ayl = *(const short8*)&ybl[b1][ln*136 + ks*32 + kq*8];
        #pragma unroll
        for (int g = 0; g < 3; ++g) {
          short8 bh;
          if (g < 2) bh = W1hp[g][ks];
          else       bh = *(const short8*)&wih1hL[((w*3+2)*4+ks)*512 + lane*8];
          accY[g] = MFMA(ayh, bh,         accY[g], 0,0,0);
          accY[g] = MFMA(ayh, W1l[g][ks], accY[g], 0,0,0);
          accY[g] = MFMA(ayl, bh,         accY[g], 0,0,0);
        }
      }
    }
    ldsbar();          // single LDS-only barrier per step
  }

  // epilogue: hid (fp32) + hid^T hi/lo (bf16, FRAGMENT-LINEAR)
  {
    int c = w*16 + ln;
    #pragma unroll
    for (int rg = 0; rg < 4; ++rg)
      hidg[(size_t)(r0 + kq*4 + rg)*HD + c] = h1o[rg];
    #pragma unroll
    for (int rg = 0; rg < 4; ++rg) {
      unsigned short hh = f2b(h1o[rg]);
      unsigned short ll = f2b(h1o[rg] - b2f(hh));
      int n   = r0 + kq*4 + rg;
      int chn = n >> 9, ksn = (n >> 5) & 15, kqn = (n >> 3) & 3, jn = n & 7;
      size_t o = ((size_t)((w*8 + chn)*16 + ksn))*512
               + (size_t)(kqn*16 + ln)*8 + jn;
      hTh[o] = hh;
      hTl[o] = ll;
    }
  }
}

// ---------------- FALLBACK: R10 fused GRU (780 µs, proven) ----------------
__global__ __launch_bounds__(512, 1) void gru_fb_kernel(
    const void* __restrict__ xg,
    const void* __restrict__ bih0, const void* __restrict__ bhh0,
    const void* __restrict__ bih1, const void* __restrict__ bhh1,
    const char* __restrict__ ws, float* __restrict__ hidg,
    unsigned short* __restrict__ hTh, unsigned short* __restrict__ hTl)
{
  __shared__ __align__(16) unsigned short wih0L[49152];
  __shared__ __align__(16) unsigned short xhi[1152], xlo[1152];
  __shared__ __align__(16) unsigned short h0hi[2176], h0lo[2176];
  __shared__ __align__(16) unsigned short h1hi[2176], h1lo[2176];
  __shared__ int sp;
  const int tid  = threadIdx.x;
  const int w    = tid >> 6;
  const int lane = tid & 63;
  const int ln   = lane & 15;
  const int kq   = lane >> 4;
  const int r0   = blockIdx.x * 16;

  int xf  = probe_f32(xg,   256, &sp);
  int fb0 = probe_f32(bih0, 256, &sp);
  int fh0 = probe_f32(bhh0, 256, &sp);
  int fb1 = probe_f32(bih1, 256, &sp);
  int fh1 = probe_f32(bhh1, 256, &sp);

  const unsigned short* f0h  = (const unsigned short*)(ws+WS_F0H);
  const unsigned short* f0l  = (const unsigned short*)(ws+WS_F0L);
  const unsigned short* fr0h = (const unsigned short*)(ws+WS_FR0H);
  const unsigned short* fr0l = (const unsigned short*)(ws+WS_FR0L);
  const unsigned short* fr1h = (const unsigned short*)(ws+WS_FR1H);
  const unsigned short* fr1l = (const unsigned short*)(ws+WS_FR1L);
  const unsigned short* fr2h = (const unsigned short*)(ws+WS_FR2H);
  const unsigned short* fr2l = (const unsigned short*)(ws+WS_FR2L);

  for (int i = tid*8; i < 24576; i += 4096) {
    *(ushort4*)&wih0L[i]         = *(const ushort4*)&f0h[i];
    *(ushort4*)&wih0L[i+4]       = *(const ushort4*)&f0h[i+4];
    *(ushort4*)&wih0L[24576+i]   = *(const ushort4*)&f0l[i];
    *(ushort4*)&wih0L[24576+i+4] = *(const ushort4*)&f0l[i+4];
  }
  short8 R0h[3][4], R1h[3][4], R2h[3][4];
  #pragma unroll
  for (int g = 0; g < 3; ++g)
    #pragma unroll
    for (int ks = 0; ks < 4; ++ks) {
      int fi = (w*3+g)*4 + ks;
      R0h[g][ks] = *(const short8*)&fr0h[fi*512 + lane*8];
      R1h[g][ks] = *(const short8*)&fr1h[fi*512 + lane*8];
      R2h[g][ks] = *(const short8*)&fr2h[fi*512 + lane*8];
      pinv(R0h[g][ks]); pinv(R1h[g][ks]); pinv(R2h[g][ks]);
    }
  const int nr = 16*w + ln;
  float brc0 = ldr1(bih0,nr,fb0)     + ldr1(bhh0,nr,fh0);
  float bzc0 = ldr1(bih0,nr+128,fb0) + ldr1(bhh0,nr+128,fh0);
  float bin0 = ldr1(bih0,nr+256,fb0);
  float bhn0 = ldr1(bhh0,nr+256,fh0);
  float brc1 = ldr1(bih1,nr,fb1)     + ldr1(bhh1,nr,fh1);
  float bzc1 = ldr1(bih1,nr+128,fb1) + ldr1(bhh1,nr+128,fh1);
  float bin1 = ldr1(bih1,nr+256,fb1);
  float bhn1 = ldr1(bhh1,nr+256,fh1);

  for (int i = tid; i < 2176; i += 512) {
    h0hi[i] = 0; h0lo[i] = 0; h1hi[i] = 0; h1lo[i] = 0;
  }
  float h0o[4] = {0.f,0.f,0.f,0.f};
  float h1o[4] = {0.f,0.f,0.f,0.f};
  __syncthreads();

  #pragma unroll 1
  for (int t = 0; t < TSTEPS; ++t) {
    {
      int i0 = tid*2, m = i0 >> 6, f = i0 & 63;
      size_t base = ((size_t)(r0+m)*TSTEPS + t)*64 + f;
      float v0, v1;
      if (xf) { float2 xv = *(const float2*)((const float*)xg + base); v0 = xv.x; v1 = xv.y; }
      else { ushort2 u = *(const ushort2*)((const unsigned short*)xg + base); v0 = b2f(u.x); v1 = b2f(u.y); }
      unsigned short a0 = f2b(v0), a1 = f2b(v1);
      xhi[m*72+f] = a0;              xhi[m*72+f+1] = a1;
      xlo[m*72+f] = f2b(v0-b2f(a0)); xlo[m*72+f+1] = f2b(v1-b2f(a1));
    }
    __syncthreads();
    f32x4 acc[4];
    #pragma unroll
    for (int g = 0; g < 4; ++g) acc[g] = f4zero();
    #pragma unroll
    for (int ks = 0; ks < 2; ++ks) {
      short8 axh = *(const short8*)&xhi[ln*72 + ks*32 + kq*8];
      short8 axl = *(const short8*)&xlo[ln*72 + ks*32 + kq*8];
      #pragma unroll
      for (int g = 0; g < 3; ++g) {
        int fi = (w*3+g)*2 + ks;
        short8 bh = *(const short8*)&wih0L[fi*512 + lane*8];
        short8 bl = *(const short8*)&wih0L[24576 + fi*512 + lane*8];
        acc[g] = MFMA(axh, bh, acc[g], 0,0,0);
        acc[g] = MFMA(axh, bl, acc[g], 0,0,0);
        acc[g] = MFMA(axl, bh, acc[g], 0,0,0);
      }
    }
    #pragma unroll
    for (int ks = 0; ks < 4; ++ks) {
      short8 ahh = *(const short8*)&h0hi[ln*136 + ks*32 + kq*8];
      short8 ahl = *(const short8*)&h0lo[ln*136 + ks*32 + kq*8];
      #pragma unroll
      for (int g = 0; g < 3; ++g) {
        int tgt = (g==2) ? 3 : g;
        short8 bl = *(const short8*)&fr0l[((w*3+g)*4+ks)*512 + lane*8];
        acc[tgt] = MFMA(ahh, R0h[g][ks], acc[tgt], 0,0,0);
        acc[tgt] = MFMA(ahh, bl,         acc[tgt], 0,0,0);
        acc[tgt] = MFMA(ahl, R0h[g][ks], acc[tgt], 0,0,0);
      }
    }
    unsigned short nh[4], nl[4];
    #pragma unroll
    for (int rg = 0; rg < 4; ++rg) {
      float r  = sigm(acc[0][rg] + brc0);
      float z  = sigm(acc[1][rg] + bzc0);
      float nn = tanhfast(acc[2][rg] + bin0 + r*(acc[3][rg] + bhn0));
      float h  = nn + z*(h0o[rg] - nn);
      h0o[rg] = h;
      unsigned short hh = f2b(h);
      nh[rg] = hh; nl[rg] = f2b(h - b2f(hh));
    }
    __syncthreads();
    #pragma unroll
    for (int rg = 0; rg < 4; ++rg) {
      int off = (kq*4+rg)*136 + w*16 + ln;
      h0hi[off] = nh[rg]; h0lo[off] = nl[rg];
    }
    __syncthreads();
    #pragma unroll
    for (int g = 0; g < 4; ++g) acc[g] = f4zero();
    #pragma unroll
    for (int ks = 0; ks < 4; ++ks) {
      short8 ayh = *(const short8*)&h0hi[ln*136 + ks*32 + kq*8];
      short8 ayl = *(const short8*)&h0lo[ln*136 + ks*32 + kq*8];
      short8 a1h = *(const short8*)&h1hi[ln*136 + ks*32 + kq*8];
      short8 a1l = *(const short8*)&h1lo[ln*136 + ks*32 + kq*8];
      #pragma unroll
      for (int g = 0; g < 3; ++g) {
        int tgtI = (g==2) ? 2 : g;
        int tgtH = (g==2) ? 3 : g;
        short8 blI = *(const short8*)&fr1l[((w*3+g)*4+ks)*512 + lane*8];
        short8 blH = *(const short8*)&fr2l[((w*3+g)*4+ks)*512 + lane*8];
        acc[tgtI] = MFMA(ayh, R1h[g][ks], acc[tgtI], 0,0,0);
        acc[tgtI] = MFMA(ayh, blI,        acc[tgtI], 0,0,0);
        acc[tgtI] = MFMA(ayl, R1h[g][ks], acc[tgtI], 0,0,0);
        acc[tgtH] = MFMA(a1h, R2h[g][ks], acc[tgtH], 0,0,0);
        acc[tgtH] = MFMA(a1h, blH,        acc[tgtH], 0,0,0);
        acc[tgtH] = MFMA(a1l, R2h[g][ks], acc[tgtH], 0,0,0);
      }
    }
    #pragma unroll
    for (int rg = 0; rg < 4; ++rg) {
      float r  = sigm(acc[0][rg] + brc1);
      float z  = sigm(acc[1][rg] + bzc1);
      float nn = tanhfast(acc[2][rg] + bin1 + r*(acc[3][rg] + bhn1));
      float h  = nn + z*(h1o[rg] - nn);
      h1o[rg] = h;
      unsigned short hh = f2b(h);
      nh[rg] = hh; nl[rg] = f2b(h - b2f(hh));
    }
    __syncthreads();
    #pragma unroll
    for (int rg = 0; rg < 4; ++rg) {
      int off = (kq*4+rg)*136 + w*16 + ln;
      h1hi[off] = nh[rg]; h1lo[off] = nl[rg];
    }
  }
  {
    int c = w*16 + ln;
    #pragma unroll
    for (int rg = 0; rg < 4; ++rg)
      hidg[(size_t)(r0 + kq*4 + rg)*HD + c] = h1o[rg];
    #pragma unroll
    for (int rg = 0; rg < 4; ++rg) {
      unsigned short hh = f2b(h1o[rg]);
      unsigned short ll = f2b(h1o[rg] - b2f(hh));
      int n   = r0 + kq*4 + rg;
      int chn = n >> 9, ksn = (n >> 5) & 15, kqn = (n >> 3) & 3, jn = n & 7;
      size_t o = ((size_t)((w*8 + chn)*16 + ksn))*512
               + (size_t)(kqn*16 + ln)*8 + jn;
      hTh[o] = hh;
      hTl[o] = ll;
    }
  }
}

// ---------------- s_j / s_i prep (fp32), 256 threads (R7-proven) ----------
template<bool WT32>
__device__ void sprep_body(
    const float* hidg, const void* wt, const void* bt, const void* a,
    int f_bt, int f_a, float* sjg, float* sig, float* hL, float* redb)
{
  const int tid = threadIdx.x;
  const int r0  = blockIdx.x * 16;
  for (int i = tid; i < 2048; i += 256) hL[i] = hidg[(size_t)r0*128 + i];
  __syncthreads();
  const int r = tid >> 4, cg = tid & 15, c0 = cg*8;
  float sjp = 0.f, sip = 0.f;
  #pragma unroll 1
  for (int cc = 0; cc < 8; ++cc) {
    int cI = c0 + cc;
    float acc = ldr1(bt, cI, f_bt);
    #pragma unroll 4
    for (int kq = 0; kq < 32; ++kq) {
      int k = kq*4;
      float4 wv = ldg4c<WT32>(wt, (size_t)cI*128 + k);
      float4 h = *(const float4*)&hL[r*128 + k];
      acc += wv.x*h.x + wv.y*h.y + wv.z*h.z + wv.w*h.w;
    }
    sjp += acc * ldr1(a, cI, f_a);
    sip += acc * ldr1(a, cI + 128, f_a);
  }
  redb[(r*16+cg)*2]   = sjp;
  redb[(r*16+cg)*2+1] = sip;
  __syncthreads();
  if (tid < 32) {
    int r2 = tid >> 1, wh = tid & 1;
    float s = 0.f;
    for (int g = 0; g < 16; ++g) s += redb[(r2*16+g)*2 + wh];
    if (wh == 0) sjg[r0+r2] = s; else sig[r0+r2] = s;
  }
}

__global__ __launch_bounds__(256) void sprep_kernel(
    const float* hidg, const void* wt, const void* bt, const void* a,
    float* sjg, float* sig)
{
  __shared__ float hL[2048];
  __shared__ float redb[512];
  __shared__ int sp;
  int f_wt = probe_f32(wt, 256, &sp);
  int f_bt = probe_f32(bt, 128, &sp);
  int f_a  = probe_f32(a,  256, &sp);
  if (f_wt) sprep_body<true >(hidg, wt, bt, a, f_bt, f_a, sjg, sig, hL, redb);
  else      sprep_body<false>(hidg, wt, bt, a, f_bt, f_a, sjg, sig, hL, redb);
}

// ---------------- MFMA attention + residual + MLP tail --------------------
// R11: back to 16-row/256-block R7 form, PLUS:
//  (1) amdgpu_waves_per_eu(2,2) — the knob PROVEN effective on 512-thread
//      kernels (gru1: 128 VGPR) — R10 showed attn got a 52-VGPR allocation,
//      serializing the 32 B-loads per chunk at full L2 latency each.
//  (2) accO split into 4 accumulators by ks&3: dependent MFMA chain
//      384 -> 96, giving the scheduler independent streams to overlap
//      with loads (fp32 reassoc of PV sum — accepted; absmax stable).
template<bool PW32>
__device__ void attn_body(
    const float* sjg, const float* sig, const float* hidg,
    const unsigned short* hTh, const unsigned short* hTl,
    const void* wfc, const void* bfc, const void* wp1, const void* bp1,
    const void* wp2, const void* bp2,
    int f_bfc, int f_bp1, int f_wp2, float* outg,
    float* sjs, unsigned short* Pbuf, float* Obuf, float* redm,
    float* siL, float* miL, float* Zb)
{
  const int tid = threadIdx.x;
  const int w = tid >> 6, lane = tid & 63, ln = lane & 15, kq = lane >> 4;
  const int r0 = blockIdx.x * 16;

  for (int i = tid; i < 4096; i += 512) sjs[i] = sjg[i];
  __syncthreads();
  float mx = -1e30f;
  for (int i = tid; i < 4096; i += 512) mx = fmaxf(mx, sjs[i]);
  redm[tid] = mx;
  __syncthreads();
  for (int s = 256; s > 0; s >>= 1) {
    if (tid < s) redm[tid] = fmaxf(redm[tid], redm[tid+s]);
    __syncthreads();
  }
  if (tid < 16) {
    float si = sig[r0 + tid];
    siL[tid] = si;
    miL[tid] = lrelu(si + redm[0]);
  }
  __syncthreads();

  float zp[16];
  #pragma unroll
  for (int i = 0; i < 16; ++i) zp[i] = 0.f;
  f32x4 accO4[4];
  #pragma unroll
  for (int i = 0; i < 4; ++i) accO4[i] = f4zero();
  const int col = w*16 + ln;

  #define GENP(CH, BASE)                                                    \
    {                                                                       \
      unsigned short* Phi_ = (BASE);                                        \
      unsigned short* Plo_ = (BASE) + 8320;                                 \
      float sjv = sjs[(CH)*512 + tid];                                      \
      _Pragma("unroll")                                                     \
      for (int i = 0; i < 16; ++i) {                                        \
        float v = lrelu(siL[i] + sjv);                                      \
        float p = __expf(v - miL[i]);                                       \
        zp[i] += p;                                                         \
        unsigned short hh = f2b(p);                                         \
        Phi_[i*520 + tid] = hh;                                             \
        Plo_[i*520 + tid] = f2b(p - b2f(hh));                               \
      }                                                                     \
    }

  GENP(0, Pbuf);
  __syncthreads();

  #pragma unroll 1
  for (int ch = 0; ch < 8; ++ch) {
    const int b = ch & 1;
    unsigned short* Phi = Pbuf + b*16640;
    unsigned short* Plo = Phi + 8320;
    #pragma unroll
    for (int ks = 0; ks < 16; ++ks) {
      const int ai = ks & 3;
      short8 Ah = *(const short8*)&Phi[ln*520 + ks*32 + kq*8];
      short8 Al = *(const short8*)&Plo[ln*520 + ks*32 + kq*8];
      size_t bo = ((size_t)((w*8 + ch)*16 + ks))*512 + (size_t)lane*8;
      short8 Bh = *(const short8*)&hTh[bo];
      short8 Bl = *(const short8*)&hTl[bo];
      accO4[ai] = MFMA(Ah, Bh, accO4[ai], 0,0,0);
      accO4[ai] = MFMA(Ah, Bl, accO4[ai], 0,0,0);
      accO4[ai] = MFMA(Al, Bh, accO4[ai], 0,0,0);
    }
    if (ch < 7) GENP(ch+1, Pbuf + (b^1)*16640);
    __syncthreads();
  }
  #undef GENP

  {
    f32x4 accO;
    #pragma unroll
    for (int e = 0; e < 4; ++e)
      accO[e] = (accO4[0][e] + accO4[1][e]) + (accO4[2][e] + accO4[3][e]);
    #pragma unroll
    for (int rg = 0; rg < 4; ++rg)
      Obuf[(kq*4+rg)*128 + col] = accO[rg];
  }

  float* zarr = (float*)Pbuf;
  #pragma unroll
  for (int i = 0; i < 16; ++i) zarr[i*512 + tid] = zp[i];
  __syncthreads();
  {
    int row = tid >> 5, t0 = tid & 31;
    float s = 0.f;
    #pragma unroll
    for (int k = 0; k < 16; ++k) s += zarr[row*512 + t0 + 32*k];
    redm[row*32 + t0] = s;
  }
  __syncthreads();
  if (tid < 16) {
    float s = 0.f;
    for (int g = 0; g < 32; ++g) s += redm[tid*32 + g];
    Zb[tid] = s;
  }
  __syncthreads();

  {
    int e0 = tid*4, row = e0 >> 7, c = e0 & 127;
    float zi = Zb[row];
    #pragma unroll
    for (int e = 0; e < 4; ++e)
      Obuf[e0+e] = Obuf[e0+e]/zi + hidg[(size_t)(r0+row)*128 + c + e];
  }
  __syncthreads();

  float* h3f = sjs;
  {
    int o0 = tid*4, row = o0 >> 7, c = o0 & 127;
    #pragma unroll 1
    for (int e = 0; e < 4; ++e) {
      int cI = c + e;
      float acc = ldr1(bfc, cI, f_bfc);
      #pragma unroll 4
      for (int k4 = 0; k4 < 32; ++k4) {
        int k = k4*4;
        float4 wv = ldg4c<PW32>(wfc, (size_t)cI*128 + k);
        float4 h = *(const float4*)&Obuf[row*128 + k];
        acc += wv.x*h.x + wv.y*h.y + wv.z*h.z + wv.w*h.w;
      }
      h3f[row*128 + cI] = lrelu(acc);
    }
  }
  __syncthreads();

  float* h1f = (float*)Pbuf;
  {
    int o0 = tid*8, row = o0 >> 8, c = o0 & 255;
    #pragma unroll 1
    for (int e = 0; e < 8; ++e) {
      int cI = c + e;
      float acc = ldr1(bp1, cI, f_bp1);
      #pragma unroll 4
      for (int k4 = 0; k4 < 32; ++k4) {
        int k = k4*4;
        float4 wv = ldg4c<PW32>(wp1, (size_t)cI*128 + k);
        float4 h = *(const float4*)&h3f[row*128 + k];
        acc += wv.x*h.x + wv.y*h.y + wv.z*h.z + wv.w*h.w;
      }
      h1f[row*256 + cI] = 0.5f*acc*(1.0f + erff(acc*0.70710678118f));
    }
  }
  __syncthreads();

  {
    int row = tid >> 5, t0 = tid & 31;
    float s = 0.f;
    #pragma unroll
    for (int k = 0; k < 8; ++k) {
      int cI = t0 + 32*k;
      s += h1f[row*256 + cI] * ldr1(wp2, cI, f_wp2);
    }
    redm[row*32 + t0] = s;
  }
  __syncthreads();
  if (tid < 16) {
    float acc = ldr1(bp2, 0, f_bp1);
    for (int g = 0; g < 32; ++g) acc += redm[tid*32 + g];
    outg[r0 + tid] = acc;
  }
}

__global__ __launch_bounds__(512) __attribute__((amdgpu_waves_per_eu(2,2)))
void attn_kernel(
    const float* sjg, const float* sig, const float* hidg,
    const unsigned short* hTh, const unsigned short* hTl,
    const void* wfc, const void* bfc, const void* wp1, const void* bp1,
    const void* wp2, const void* bp2, float* outg)
{
  __shared__ float sjs[4096];
  __shared__ __align__(16) unsigned short Pbuf[33280];   // 2 x (Phi|Plo)
  __shared__ float Obuf[2048];
  __shared__ float redm[512];
  __shared__ float siL[16], miL[16], Zb[16];
  __shared__ int sp;
  int f_wfc = probe_f32(wfc, 256, &sp);
  int f_bfc = probe_f32(bfc, 128, &sp);
  int f_bp1 = probe_f32(bp1, 256, &sp);
  int f_wp2 = probe_f32(wp2, 256, &sp);
  if (f_wfc) attn_body<true >(sjg, sig, hidg, hTh, hTl, wfc, bfc, wp1, bp1,
                              wp2, bp2, f_bfc, f_bp1, f_wp2, outg,
                              sjs, Pbuf, Obuf, redm, siL, miL, Zb);
  else       attn_body<false>(sjg, sig, hidg, hTh, hTl, wfc, bfc, wp1, bp1,
                              wp2, bp2, f_bfc, f_bp1, f_wp2, outg,
                              sjs, Pbuf, Obuf, redm, siL, miL, Zb);
}

extern "C" void kernel_launch(void* const* d_in, const int* in_sizes, int n_in,
                              void* d_out, int out_size, void* d_ws, size_t ws_size,
                              hipStream_t stream)
{
  float* out = (float*)d_out;
  const int expected[18] = {15728640,24576,49152,384,384,49152,49152,384,384,
                            16384,128,256,16384,128,32768,256,256,1};
  int bad = 0;
  if (n_in != 18 || out_size != 4096) bad = 1600;
  else for (int i = 0; i < 18; ++i) if (in_sizes[i] != expected[i]) { bad = 1600; break; }
  if (!bad && ws_size < (size_t)WS_BASE) bad = 1664;
  if (bad) { diag_kernel<<<16, 256, 0, stream>>>(out, (float)bad); return; }

  char* ws = (char*)d_ws;
  float*          sj  = (float*)(ws + WS_SJ);
  float*          si  = (float*)(ws + WS_SI);
  float*          hid = (float*)(ws + WS_HID);
  unsigned short* hTh = (unsigned short*)(ws + WS_HTH);
  unsigned short* hTl = (unsigned short*)(ws + WS_HTL);

  repack_kernel<<<256, 256, 0, stream>>>(d_in[1], d_in[2], d_in[5], d_in[6], ws);
  if (ws_size >= WS_FULL) {
    unsigned* y0p = (unsigned*)(ws + WS_Y0P);
    gru0_kernel<<<256, 1024, 0, stream>>>(d_in[0], d_in[3], d_in[4], ws, y0p);
    gru1_kernel<<<256, 512, 0, stream>>>(d_in[7], d_in[8], ws, y0p,
                                         hid, hTh, hTl);
  } else {
    gru_fb_kernel<<<256, 512, 0, stream>>>(d_in[0], d_in[3], d_in[4],
                                           d_in[7], d_in[8], ws, hid, hTh, hTl);
  }
  sprep_kernel<<<256, 256, 0, stream>>>(hid, d_in[9], d_in[10], d_in[11], sj, si);
  attn_kernel<<<256, 512, 0, stream>>>(sj, si, hid, hTh, hTl,
                                       d_in[12], d_in[13], d_in[14], d_in[15],
                                       d_in[16], d_in[17], out);
}